// Round 9
// baseline (336.013 us; speedup 1.0000x reference)
//
#include <hip/hip_runtime.h>

// MemoryReader: B=4, CK=64, N=8192, M=1024, CV=512. Inputs fp32, output fp32.
// logits s[n,m] = (2*mk.qk - |mk|^2)/8; softmax over n; out = mv @ P.
// R6: 292us k_main latency-bound (4 waves/CU). R7: N-split = L2 thrash (FETCH 430MB).
// R8: cs=8 lockstep streaming, 196us, but grid 512 = 2 blocks/CU caps occupancy 23%,
//     VALU 31% / MFMA 14% -> still serialization-bound.
// R9: m-tile 32 -> grid 1024 (4 blocks/CU, 16 waves/CU), per-wave step work halved;
//     dbuf lds_p + prefetch-before-barrier -> ONE barrier per step;
//     k_prep LDS-transpose for coalesced writes. Streaming swizzle unchanged.

typedef unsigned short ushort_t;
typedef unsigned int uint_t;
typedef __attribute__((ext_vector_type(8))) short short8;
typedef __attribute__((ext_vector_type(4))) float floatx4;

#define MFMA16(a, b, c) __builtin_amdgcn_mfma_f32_16x16x32_bf16((a), (b), (c), 0, 0, 0)

__device__ __forceinline__ ushort_t f2b(float f) {
    uint_t b = __float_as_uint(f);
    b += 0x7FFFu + ((b >> 16) & 1u);   // RNE to bf16
    return (ushort_t)(b >> 16);
}

#define BB 4
#define CK 64
#define NN 8192
#define MM 1024
#define CV 512
#define NSTEP 128     // 64-token steps over full n-range

// ---- module-scope scratch (fully rewritten every call) ----
__device__ __align__(16) ushort_t g_mkT[BB * NN * CK];   // 4 MiB  bf16 mk^T [b][n][c]
__device__ __align__(16) float    g_asq8[BB * NN];       // 128 KiB (sum mk^2)/8
__device__ __align__(16) ushort_t g_mvb[BB * CV * NN];   // 32 MiB bf16 mv [b][c][n]

// ---------------------------------------------------------------------------
// K0: g_mkT[b][n][c] = bf16(mk[b][c][n]); g_asq8 = (sum_c mk^2)/8 (fp32).
// LDS transpose: coalesced fp32 loads (lanes along n) -> T[n][c] (pad 65) ->
// coalesced 16B bf16 stores (4 lanes cover one 128B row). 512 blocks.
// ---------------------------------------------------------------------------
__global__ __launch_bounds__(256) void k_prep(const float* __restrict__ mk) {
    __shared__ float T[64][65];
    int blk = blockIdx.x;          // 0..511
    int b = blk >> 7;
    int n0 = (blk & 127) * 64;
    int tid = threadIdx.x;

#pragma unroll
    for (int it = 0; it < 16; it++) {
        int c = it * 4 + (tid >> 6);
        int n = tid & 63;
        T[n][c] = mk[(size_t)(b * CK + c) * NN + n0 + n];
    }
    __syncthreads();

    int n = tid >> 2;              // 0..63
    int seg = tid & 3;             // 0..3 (16 c each)
    float s = 0.f;
    ushort_t v[16];
#pragma unroll
    for (int i = 0; i < 16; i++) {
        float f = T[n][seg * 16 + i];
        s += f * f;
        v[i] = f2b(f);
    }
    uint4 q0, q1;
    q0.x = (uint_t)v[0] | ((uint_t)v[1] << 16);
    q0.y = (uint_t)v[2] | ((uint_t)v[3] << 16);
    q0.z = (uint_t)v[4] | ((uint_t)v[5] << 16);
    q0.w = (uint_t)v[6] | ((uint_t)v[7] << 16);
    q1.x = (uint_t)v[8] | ((uint_t)v[9] << 16);
    q1.y = (uint_t)v[10] | ((uint_t)v[11] << 16);
    q1.z = (uint_t)v[12] | ((uint_t)v[13] << 16);
    q1.w = (uint_t)v[14] | ((uint_t)v[15] << 16);
    ushort_t* dst = g_mkT + (size_t)(b * NN + n0 + n) * CK + seg * 16;
    *(uint4*)dst = q0;
    *(uint4*)(dst + 8) = q1;

    s += __shfl_xor(s, 1, 64);
    s += __shfl_xor(s, 2, 64);
    if (seg == 0) g_asq8[b * NN + n0 + n] = s * 0.125f;
}

// ---------------------------------------------------------------------------
// K0b: g_mvb = bf16(mv), flat, 8 elems/thread, fully coalesced.
// ---------------------------------------------------------------------------
__global__ __launch_bounds__(256) void k_mvconv(const float* __restrict__ mv) {
    size_t t = (size_t)blockIdx.x * 256 + threadIdx.x;
    const float4* s = (const float4*)mv + t * 2;
    float4 x = s[0], y = s[1];
    uint4 q;
    q.x = (uint_t)f2b(x.x) | ((uint_t)f2b(x.y) << 16);
    q.y = (uint_t)f2b(x.z) | ((uint_t)f2b(x.w) << 16);
    q.z = (uint_t)f2b(y.x) | ((uint_t)f2b(y.y) << 16);
    q.w = (uint_t)f2b(y.z) | ((uint_t)f2b(y.w) << 16);
    ((uint4*)g_mvb)[t] = q;
}

// ---------------------------------------------------------------------------
// K1: fused. grid 1024 = mt32(32) x cs(8) x b(4), bx = mt32*32 + cs*4 + b ->
// bx%32 const per (b,cs): all 32 m-blocks of a group on one XCD, lockstep
// streams. 4 blocks/CU -> 16 waves/CU.
// Block tile: m=32, c=64, per step n=64. Waves: mh=w>>1 (m half), nh=w&1 (n half).
//  G1: wave computes S[mh*16 rows][nh*32 cols] (2 nt x 2 kchunk MFMA) -> exp ->
//      P bf16 -> lds_p[buf] (+ dpart partial denoms).
//  prefetch ktile[buf^1]+asq[buf^1] (async); ONE barrier (vmcnt drain = ktile
//      landed, lgkm = P visible).
//  G2: wave's 16 c-rows x 32 m: P from lds_p[buf], mv direct 16B global.
// Hazard audit: every cross-wave LDS reuse pair is separated by >=1 barrier.
// MFMA layouts (m89/m91): A[row=l15][k=quad*8+j], B same, D row=quad*4+r (A row),
// col=l15 (B row).
// ---------------------------------------------------------------------------
__global__ __launch_bounds__(256, 4) void k_main(const float* __restrict__ qk,
                                                 float* __restrict__ out) {
    // ktile chunk layout: 16B chunk (cq 0..7, n 0..63) at ushort (cq*64+n)*8.
    __shared__ __align__(16) ushort_t ktile[2][64 * 64];   // 2 x 8 KiB
    __shared__ __align__(16) ushort_t lds_p[2][32 * 72];   // 2 x 4.5 KiB, pitch 72
    __shared__ __align__(16) float    asq_s[2][64];
    __shared__ float denom_s[2][32];

    int bx = blockIdx.x;
    int mt32 = bx >> 5;          // 0..31
    int cs = (bx >> 2) & 7;      // 0..7
    int b = bx & 3;              // 0..3
    int c0 = cs * 64;
    int m0 = mt32 * 32;

    int tid = threadIdx.x;
    int w = tid >> 6;
    int lane = tid & 63;
    int quad = lane >> 4;
    int l15 = lane & 15;
    int mh = w >> 1;             // m half (16 rows)
    int nh = w & 1;              // n half (32 cols)

    // Q fragments: wave's 16 m-rows (K=64, 2 chunks), in regs all loop.
    int mrow = m0 + mh * 16 + l15;
    short8 aq0, aq1;
#pragma unroll
    for (int j = 0; j < 8; j++) {
        aq0[j] = (short)f2b(qk[(size_t)(b * CK + quad * 8 + j) * MM + mrow]);
        aq1[j] = (short)f2b(qk[(size_t)(b * CK + 32 + quad * 8 + j) * MM + mrow]);
    }

    const ushort_t* mkTb = g_mkT + (size_t)b * NN * CK;

    floatx4 acc[2];
    acc[0] = (floatx4){0.f, 0.f, 0.f, 0.f};
    acc[1] = (floatx4){0.f, 0.f, 0.f, 0.f};
    float dpart[4] = {0.f, 0.f, 0.f, 0.f};

    // ---- prologue: stage ktile[0] + asq[0] ----
#pragma unroll
    for (int gi = 0; gi < 2; gi++) {
        int g2 = w + gi * 4;
        const ushort_t* gsrc = mkTb + (size_t)lane * CK + g2 * 8;
        __builtin_amdgcn_global_load_lds(
            (const __attribute__((address_space(1))) unsigned int*)gsrc,
            (__attribute__((address_space(3))) unsigned int*)&ktile[0][g2 * 512], 16, 0, 0);
    }
    if (w == 0) {
        __builtin_amdgcn_global_load_lds(
            (const __attribute__((address_space(1))) unsigned int*)(g_asq8 + (size_t)b * NN + lane),
            (__attribute__((address_space(3))) unsigned int*)&asq_s[0][0], 4, 0, 0);
    }
    __syncthreads();

    for (int step = 0; step < NSTEP; step++) {
        int buf = step & 1;
        int n0 = step * 64;

        // ---- G1: 16m x 32n scores -> exp -> P(bf16) lds_p[buf] ----
#pragma unroll
        for (int tt = 0; tt < 2; tt++) {
            int col = nh * 32 + tt * 16 + l15;            // n within step tile
            const ushort_t* kr = &ktile[buf][(quad * 64 + col) * 8];
            short8 kb0 = *(const short8*)kr;
            short8 kb1 = *(const short8*)(kr + 2048);     // chunk quad+4
            floatx4 d = {0.f, 0.f, 0.f, 0.f};
            d = MFMA16(aq0, kb0, d);
            d = MFMA16(aq1, kb1, d);
            float sa = asq_s[buf][col];
#pragma unroll
            for (int r = 0; r < 4; r++) {
                float p = __expf(d[r] * 0.25f - sa);
                dpart[r] += p;
                lds_p[buf][(mh * 16 + quad * 4 + r) * 72 + col] = f2b(p);
            }
        }

        // ---- prefetch next ktile/asq into buf^1 (drains at the barrier) ----
        if (step + 1 < NSTEP) {
            int n1 = n0 + 64;
#pragma unroll
            for (int gi = 0; gi < 2; gi++) {
                int g2 = w + gi * 4;
                const ushort_t* gsrc = mkTb + (size_t)(n1 + lane) * CK + g2 * 8;
                __builtin_amdgcn_global_load_lds(
                    (const __attribute__((address_space(1))) unsigned int*)gsrc,
                    (__attribute__((address_space(3))) unsigned int*)&ktile[buf ^ 1][g2 * 512], 16, 0, 0);
            }
            if (w == 0) {
                __builtin_amdgcn_global_load_lds(
                    (const __attribute__((address_space(1))) unsigned int*)(g_asq8 + (size_t)b * NN + n1 + lane),
                    (__attribute__((address_space(3))) unsigned int*)&asq_s[buf ^ 1][0], 4, 0, 0);
            }
        }

        __syncthreads();   // P[buf] visible; ktile[buf^1] landed (vmcnt drain)

        // ---- G2: wave's 16 c-rows x 32 m += mv-tile x P-tile ----
#pragma unroll
        for (int kc = 0; kc < 2; kc++) {
            short8 pb0 = *(const short8*)&lds_p[buf][(0 * 16 + l15) * 72 + kc * 32 + quad * 8];
            short8 pb1 = *(const short8*)&lds_p[buf][(1 * 16 + l15) * 72 + kc * 32 + quad * 8];
            size_t vidx = (size_t)(b * CV + c0 + w * 16 + l15) * NN + n0 + kc * 32 + quad * 8;
            short8 va = *(const short8*)(g_mvb + vidx);
            acc[0] = MFMA16(va, pb0, acc[0]);
            acc[1] = MFMA16(va, pb1, acc[1]);
        }
        // no second barrier: G1(step+1) writes lds_p[buf^1]/reads ktile[buf^1]
    }

    // ---- epilogue: denom exchange (two n-half partials per m-row) ----
#pragma unroll
    for (int off = 1; off < 16; off <<= 1) {
#pragma unroll
        for (int r = 0; r < 4; r++) dpart[r] += __shfl_xor(dpart[r], off, 64);
    }
    if (l15 == 0) {
#pragma unroll
        for (int r = 0; r < 4; r++) denom_s[nh][mh * 16 + quad * 4 + r] = dpart[r];
    }
    __syncthreads();

#pragma unroll
    for (int mt = 0; mt < 2; mt++) {
        int m = mt * 16 + l15;
        float rdm = 1.0f / (denom_s[0][m] + denom_s[1][m]);
#pragma unroll
        for (int r = 0; r < 4; r++) {
            size_t o = (size_t)(b * CV + c0 + w * 16 + quad * 4 + r) * MM + m0 + m;
            out[o] = acc[mt][r] * rdm;
        }
    }
}

// ---------------------------------------------------------------------------
// launch — inputs identified BY SIZE.
// ---------------------------------------------------------------------------
extern "C" void kernel_launch(void* const* d_in, const int* in_sizes, int n_in,
                              void* d_out, int out_size, void* d_ws, size_t ws_size,
                              hipStream_t stream) {
    const float* mk = nullptr;   // 2,097,152
    const float* qk = nullptr;   //   262,144
    const float* mv = nullptr;   // 16,777,216
    for (int i = 0; i < n_in; i++) {
        if (in_sizes[i] == BB * CK * NN)      mk = (const float*)d_in[i];
        else if (in_sizes[i] == BB * CK * MM) qk = (const float*)d_in[i];
        else if (in_sizes[i] == BB * CV * NN) mv = (const float*)d_in[i];
    }
    float* out = (float*)d_out;
    (void)d_ws; (void)ws_size; (void)out_size;

    const size_t mv_elems = (size_t)BB * CV * NN;

    k_prep<<<(BB * NN) / 64, 256, 0, stream>>>(mk);
    k_mvconv<<<(int)(mv_elems / (8 * 256)), 256, 0, stream>>>(mv);
    k_main<<<32 * 8 * BB, 256, 0, stream>>>(qk, out);
}

// Round 10
// 296.235 us; speedup vs baseline: 1.1343x; 1.1343x over previous
//
#include <hip/hip_runtime.h>

// MemoryReader: B=4, CK=64, N=8192, M=1024, CV=512. Inputs fp32, output fp32.
// logits s[n,m] = (2*mk.qk - |mk|^2)/8; softmax over n; out = mv @ P.
// R8 (best 196us k_main): cs=8, 2 blk/CU. R9: 4 blk/CU but same per-CU totals ->
// regressed (occupancy isn't the wall; device totals are).
// R10: cs=4 (c-tile 128, m-tile 32) at the same 512-block / 2-per-CU shape:
// GEMM1 MFMA, exp count, ktile LDS reads all HALVE (redundancy 8->4). G2 per
// wave = 32c x 32m (8 indep accs). mkT pre-scaled by 0.25 (exact bf16 exponent
// shift) kills the per-exp multiply. Single barrier/step, dbuf prefetch.

typedef unsigned short ushort_t;
typedef unsigned int uint_t;
typedef __attribute__((ext_vector_type(8))) short short8;
typedef __attribute__((ext_vector_type(4))) float floatx4;

#define MFMA16(a, b, c) __builtin_amdgcn_mfma_f32_16x16x32_bf16((a), (b), (c), 0, 0, 0)

__device__ __forceinline__ ushort_t f2b(float f) {
    uint_t b = __float_as_uint(f);
    b += 0x7FFFu + ((b >> 16) & 1u);   // RNE to bf16
    return (ushort_t)(b >> 16);
}

#define BB 4
#define CK 64
#define NN 8192
#define MM 1024
#define CV 512
#define NSTEP 128     // 64-token steps over full n-range

// ---- module-scope scratch (fully rewritten every call) ----
__device__ __align__(16) ushort_t g_mkT[BB * NN * CK];   // 4 MiB  bf16 0.25*mk^T [b][n][c]
__device__ __align__(16) float    g_asq8[BB * NN];       // 128 KiB (sum mk^2)/8
__device__ __align__(16) ushort_t g_mvb[BB * CV * NN];   // 32 MiB bf16 mv [b][c][n]

// ---------------------------------------------------------------------------
// K0: g_mkT[b][n][c] = bf16(0.25*mk[b][c][n]); g_asq8 = (sum_c mk^2)/8 (fp32).
// LDS transpose: coalesced fp32 loads -> T[n][c] (pad 65) -> 16B bf16 stores.
// ---------------------------------------------------------------------------
__global__ __launch_bounds__(256) void k_prep(const float* __restrict__ mk) {
    __shared__ float T[64][65];
    int blk = blockIdx.x;          // 0..511
    int b = blk >> 7;
    int n0 = (blk & 127) * 64;
    int tid = threadIdx.x;

#pragma unroll
    for (int it = 0; it < 16; it++) {
        int c = it * 4 + (tid >> 6);
        int n = tid & 63;
        T[n][c] = mk[(size_t)(b * CK + c) * NN + n0 + n];
    }
    __syncthreads();

    int n = tid >> 2;              // 0..63
    int seg = tid & 3;             // 0..3 (16 c each)
    float s = 0.f;
    ushort_t v[16];
#pragma unroll
    for (int i = 0; i < 16; i++) {
        float f = T[n][seg * 16 + i];
        s += f * f;
        v[i] = f2b(f * 0.25f);     // bake the 1/4 logit scale (exact exp shift)
    }
    uint4 q0, q1;
    q0.x = (uint_t)v[0] | ((uint_t)v[1] << 16);
    q0.y = (uint_t)v[2] | ((uint_t)v[3] << 16);
    q0.z = (uint_t)v[4] | ((uint_t)v[5] << 16);
    q0.w = (uint_t)v[6] | ((uint_t)v[7] << 16);
    q1.x = (uint_t)v[8] | ((uint_t)v[9] << 16);
    q1.y = (uint_t)v[10] | ((uint_t)v[11] << 16);
    q1.z = (uint_t)v[12] | ((uint_t)v[13] << 16);
    q1.w = (uint_t)v[14] | ((uint_t)v[15] << 16);
    ushort_t* dst = g_mkT + (size_t)(b * NN + n0 + n) * CK + seg * 16;
    *(uint4*)dst = q0;
    *(uint4*)(dst + 8) = q1;

    s += __shfl_xor(s, 1, 64);
    s += __shfl_xor(s, 2, 64);
    if (seg == 0) g_asq8[b * NN + n0 + n] = s * 0.125f;
}

// ---------------------------------------------------------------------------
// K0b: g_mvb = bf16(mv), flat, 8 elems/thread, fully coalesced.
// ---------------------------------------------------------------------------
__global__ __launch_bounds__(256) void k_mvconv(const float* __restrict__ mv) {
    size_t t = (size_t)blockIdx.x * 256 + threadIdx.x;
    const float4* s = (const float4*)mv + t * 2;
    float4 x = s[0], y = s[1];
    uint4 q;
    q.x = (uint_t)f2b(x.x) | ((uint_t)f2b(x.y) << 16);
    q.y = (uint_t)f2b(x.z) | ((uint_t)f2b(x.w) << 16);
    q.z = (uint_t)f2b(y.x) | ((uint_t)f2b(y.y) << 16);
    q.w = (uint_t)f2b(y.z) | ((uint_t)f2b(y.w) << 16);
    ((uint4*)g_mvb)[t] = q;
}

// ---------------------------------------------------------------------------
// K1: fused. grid 512 = mt32(32) x cs(4) x b(4); bx = mt32*16 + cs*4 + b ->
// bx%8 const per (b,cs) group: all 32 m-blocks of a group on one XCD (lockstep
// streams; 2 groups/XCD, live window ~80KB). 2 blocks/CU, 8 waves/CU.
// Block tile: m=32, c=128, per step n=64. Waves: mh=w>>1, nh=w&1.
//  G1: wave computes S[16m][32n] (2 col-tiles x 2 kchunks = 4 MFMA, ktile 4KB)
//      -> exp(d - asq) -> P bf16 -> lds_p[buf]; dpart accumulates denoms.
//  prefetch ktile/asq[buf^1]; ONE barrier (vmcnt drain + lgkm).
//  G2: wave = 32c x 32m: 2kc x (2 ds_b128 P + 2x[1 b128 V + 2 MFMA]) = 8 MFMA,
//      8 independent accs.
// MFMA layouts (m89/m91): A[row=l15][k=quad*8+j], B same; D row=quad*4+r
// (A row), col=l15 (B row).
// ---------------------------------------------------------------------------
__global__ __launch_bounds__(256, 2) void k_main(const float* __restrict__ qk,
                                                 float* __restrict__ out) {
    // ktile chunk layout: 16B chunk (cq 0..7, n 0..63) at ushort (cq*64+n)*8.
    __shared__ __align__(16) ushort_t ktile[2][64 * 64];   // 2 x 8 KiB
    __shared__ __align__(16) ushort_t lds_p[2][32 * 72];   // 2 x 4.5 KiB, pitch 72
    __shared__ __align__(16) float    asq_s[2][64];
    __shared__ float denom_s[2][32];

    int bx = blockIdx.x;
    int mt32 = bx >> 4;          // 0..31
    int cs = (bx >> 2) & 3;      // 0..3
    int b = bx & 3;              // 0..3
    int c0 = cs * 128;
    int m0 = mt32 * 32;

    int tid = threadIdx.x;
    int w = tid >> 6;
    int lane = tid & 63;
    int quad = lane >> 4;
    int l15 = lane & 15;
    int mh = w >> 1;             // m half (16 rows)
    int nh = w & 1;              // n half (32 cols)

    // Q fragments: wave's 16 m-rows (K=64, 2 chunks), in regs all loop.
    int mrow = m0 + mh * 16 + l15;
    short8 aq0, aq1;
#pragma unroll
    for (int j = 0; j < 8; j++) {
        aq0[j] = (short)f2b(qk[(size_t)(b * CK + quad * 8 + j) * MM + mrow]);
        aq1[j] = (short)f2b(qk[(size_t)(b * CK + 32 + quad * 8 + j) * MM + mrow]);
    }

    const ushort_t* mkTb = g_mkT + (size_t)b * NN * CK;

    floatx4 acc[2][2];           // [ctl][mt]
#pragma unroll
    for (int i = 0; i < 2; i++)
#pragma unroll
        for (int j = 0; j < 2; j++)
            acc[i][j] = (floatx4){0.f, 0.f, 0.f, 0.f};
    float dpart[4] = {0.f, 0.f, 0.f, 0.f};

    // ---- prologue: stage ktile[0] + asq[0] ----
#pragma unroll
    for (int gi = 0; gi < 2; gi++) {
        int g2 = w + gi * 4;
        const ushort_t* gsrc = mkTb + (size_t)lane * CK + g2 * 8;
        __builtin_amdgcn_global_load_lds(
            (const __attribute__((address_space(1))) unsigned int*)gsrc,
            (__attribute__((address_space(3))) unsigned int*)&ktile[0][g2 * 512], 16, 0, 0);
    }
    if (w == 0) {
        __builtin_amdgcn_global_load_lds(
            (const __attribute__((address_space(1))) unsigned int*)(g_asq8 + (size_t)b * NN + lane),
            (__attribute__((address_space(3))) unsigned int*)&asq_s[0][0], 4, 0, 0);
    }
    __syncthreads();

    for (int step = 0; step < NSTEP; step++) {
        int buf = step & 1;
        int n0 = step * 64;

        // ---- G1: 16m x 32n scores -> exp -> P(bf16) lds_p[buf] ----
#pragma unroll
        for (int tt = 0; tt < 2; tt++) {
            int col = nh * 32 + tt * 16 + l15;            // n within step tile
            const ushort_t* kr = &ktile[buf][(quad * 64 + col) * 8];
            short8 kb0 = *(const short8*)kr;
            short8 kb1 = *(const short8*)(kr + 2048);     // chunk quad+4
            floatx4 d = {0.f, 0.f, 0.f, 0.f};
            d = MFMA16(aq0, kb0, d);
            d = MFMA16(aq1, kb1, d);
            float sa = asq_s[buf][col];
#pragma unroll
            for (int r = 0; r < 4; r++) {
                float p = __expf(d[r] - sa);              // 0.25 baked into mkT
                dpart[r] += p;
                lds_p[buf][(mh * 16 + quad * 4 + r) * 72 + col] = f2b(p);
            }
        }

        // ---- prefetch next ktile/asq into buf^1 (drains at the barrier) ----
        if (step + 1 < NSTEP) {
            int n1 = n0 + 64;
#pragma unroll
            for (int gi = 0; gi < 2; gi++) {
                int g2 = w + gi * 4;
                const ushort_t* gsrc = mkTb + (size_t)(n1 + lane) * CK + g2 * 8;
                __builtin_amdgcn_global_load_lds(
                    (const __attribute__((address_space(1))) unsigned int*)gsrc,
                    (__attribute__((address_space(3))) unsigned int*)&ktile[buf ^ 1][g2 * 512], 16, 0, 0);
            }
            if (w == 0) {
                __builtin_amdgcn_global_load_lds(
                    (const __attribute__((address_space(1))) unsigned int*)(g_asq8 + (size_t)b * NN + n1 + lane),
                    (__attribute__((address_space(3))) unsigned int*)&asq_s[buf ^ 1][0], 4, 0, 0);
            }
        }

        __syncthreads();   // P[buf] visible; ktile[buf^1] landed (vmcnt drain)

        // ---- G2: wave's 32 c-rows x 32 m += mv-tile x P-tile ----
#pragma unroll
        for (int kc = 0; kc < 2; kc++) {
            short8 pb0 = *(const short8*)&lds_p[buf][(0 * 16 + l15) * 72 + kc * 32 + quad * 8];
            short8 pb1 = *(const short8*)&lds_p[buf][(1 * 16 + l15) * 72 + kc * 32 + quad * 8];
#pragma unroll
            for (int ctl = 0; ctl < 2; ctl++) {
                size_t vidx = (size_t)(b * CV + c0 + w * 32 + ctl * 16 + l15) * NN
                              + n0 + kc * 32 + quad * 8;
                short8 va = *(const short8*)(g_mvb + vidx);
                acc[ctl][0] = MFMA16(va, pb0, acc[ctl][0]);
                acc[ctl][1] = MFMA16(va, pb1, acc[ctl][1]);
            }
        }
        // no second barrier: G1(step+1) touches only buf^1 resources
    }

    // ---- epilogue: denom exchange (two n-half partials per m-row) ----
#pragma unroll
    for (int off = 1; off < 16; off <<= 1) {
#pragma unroll
        for (int r = 0; r < 4; r++) dpart[r] += __shfl_xor(dpart[r], off, 64);
    }
    if (l15 == 0) {
#pragma unroll
        for (int r = 0; r < 4; r++) denom_s[nh][mh * 16 + quad * 4 + r] = dpart[r];
    }
    __syncthreads();

#pragma unroll
    for (int mt = 0; mt < 2; mt++) {
        int m = mt * 16 + l15;
        float rdm = 1.0f / (denom_s[0][m] + denom_s[1][m]);
#pragma unroll
        for (int ctl = 0; ctl < 2; ctl++) {
#pragma unroll
            for (int r = 0; r < 4; r++) {
                int c = c0 + w * 32 + ctl * 16 + quad * 4 + r;
                out[(size_t)(b * CV + c) * MM + m0 + m] = acc[ctl][mt][r] * rdm;
            }
        }
    }
}

// ---------------------------------------------------------------------------
// launch — inputs identified BY SIZE.
// ---------------------------------------------------------------------------
extern "C" void kernel_launch(void* const* d_in, const int* in_sizes, int n_in,
                              void* d_out, int out_size, void* d_ws, size_t ws_size,
                              hipStream_t stream) {
    const float* mk = nullptr;   // 2,097,152
    const float* qk = nullptr;   //   262,144
    const float* mv = nullptr;   // 16,777,216
    for (int i = 0; i < n_in; i++) {
        if (in_sizes[i] == BB * CK * NN)      mk = (const float*)d_in[i];
        else if (in_sizes[i] == BB * CK * MM) qk = (const float*)d_in[i];
        else if (in_sizes[i] == BB * CV * NN) mv = (const float*)d_in[i];
    }
    float* out = (float*)d_out;
    (void)d_ws; (void)ws_size; (void)out_size;

    const size_t mv_elems = (size_t)BB * CV * NN;

    k_prep<<<(BB * NN) / 64, 256, 0, stream>>>(mk);
    k_mvconv<<<(int)(mv_elems / (8 * 256)), 256, 0, stream>>>(mv);
    k_main<<<32 * 4 * BB, 256, 0, stream>>>(qk, out);
}